// Round 1
// baseline (280.897 us; speedup 1.0000x reference)
//
#include <hip/hip_runtime.h>

#define M_DIM 2048
#define K_DIM 4096
#define N_DIM 4096

typedef unsigned short u16;
typedef __bf16 bf16x8 __attribute__((ext_vector_type(8)));
typedef float f32x4 __attribute__((ext_vector_type(4)));
typedef u16 u16x4 __attribute__((ext_vector_type(4)));
typedef u16 u16x8 __attribute__((ext_vector_type(8)));

// fp32 -> bf16 round-to-nearest-even
__device__ __forceinline__ u16 f2bf(float f) {
    unsigned int u = __float_as_uint(f);
    u += 0x7fffu + ((u >> 16) & 1u);
    return (u16)(u >> 16);
}

// async global->LDS, 16B per lane. LDS dest must be wave-uniform base + lane*16.
__device__ __forceinline__ void load16(const void* g, void* l) {
    __builtin_amdgcn_global_load_lds(
        (__attribute__((address_space(1))) const void*)g,
        (__attribute__((address_space(3))) void*)l,
        16, 0, 0);
}

// ---------------- kernel 1: x (M x K fp32) -> xb (M x K bf16) ----------------
__global__ __launch_bounds__(256) void conv_x(const float* __restrict__ x,
                                              u16* __restrict__ xb) {
    size_t i = ((size_t)blockIdx.x * 256 + threadIdx.x) * 4;
    float4 v = *(const float4*)(x + i);
    u16x4 o;
    o.x = f2bf(v.x); o.y = f2bf(v.y); o.z = f2bf(v.z); o.w = f2bf(v.w);
    *(u16x4*)(xb + i) = o;
}

// ------- kernel 2: Bt[n][k] = bf16( mask[k][n] != 0 ? W[k][n] : 0 ) ---------
// 64x64 tile through LDS. T stride 68 (136 B): phase-1 u16x4 writes ~conflict
// free, phase-2 strided u16 reads ~8-way (acceptable; kernel is HBM-bound).
__global__ __launch_bounds__(256) void mask_transpose(const float* __restrict__ W,
                                                      const float* __restrict__ Msk,
                                                      u16* __restrict__ Bt) {
    __shared__ __align__(16) u16 T[64][68];   // [k][n]
    const int n0 = blockIdx.x * 64;
    const int k0 = blockIdx.y * 64;
    const int t  = threadIdx.x;

    const int colq = (t & 15) * 4;   // n within tile, 4-wide
    const int row4 = t >> 4;         // k within tile, 16 rows/pass
#pragma unroll
    for (int p = 0; p < 4; ++p) {
        int row = row4 + p * 16;
        size_t g = (size_t)(k0 + row) * N_DIM + n0 + colq;
        float4 w = *(const float4*)(W + g);
        float4 m = *(const float4*)(Msk + g);
        u16x4 v;
        v.x = f2bf(m.x != 0.f ? w.x : 0.f);
        v.y = f2bf(m.y != 0.f ? w.y : 0.f);
        v.z = f2bf(m.z != 0.f ? w.z : 0.f);
        v.w = f2bf(m.w != 0.f ? w.w : 0.f);
        *(u16x4*)&T[row][colq] = v;
    }
    __syncthreads();

    const int kc  = (t & 7) * 8;     // k within tile, 8-wide
    const int nr0 = t >> 3;          // n within tile, 32 rows/pass
#pragma unroll
    for (int p = 0; p < 2; ++p) {
        int nr = nr0 + p * 32;
        u16x8 v;
#pragma unroll
        for (int i = 0; i < 8; ++i) v[i] = T[kc + i][nr];
        *(u16x8*)(Bt + (size_t)(n0 + nr) * K_DIM + k0 + kc) = v;
    }
}

// ---------------- kernel 3: C = xb @ Bt^T + bias (m97 structure) ------------
// 128x128 tile, BK=64, 4 waves in 2x2, each wave 4x4 of 16x16x32 MFMA.
__global__ __launch_bounds__(256) void gemm_bt(const u16* __restrict__ A,   // M x K bf16
                                               const u16* __restrict__ Bt,  // N x K bf16
                                               const float* __restrict__ bias,
                                               float* __restrict__ C) {
    __shared__ __align__(16) u16 As[128 * 64];
    __shared__ __align__(16) u16 Bs[128 * 64];

    const int t  = threadIdx.x;
    const int bn = blockIdx.x;
    const int bm = blockIdx.y;

    // staging: chunk c = t + 256*it covers row c>>3, cols (c&7)*8..+7.
    // LDS offset = t*16 B (+ it*4096 B) => wave-uniform base + lane*16. OK.
    const u16* gA = A  + (size_t)(bm * 128 + (t >> 3)) * K_DIM + (t & 7) * 8;
    const u16* gB = Bt + (size_t)(bn * 128 + (t >> 3)) * K_DIM + (t & 7) * 8;
    u16* lA = As + (t >> 3) * 64 + (t & 7) * 8;
    u16* lB = Bs + (t >> 3) * 64 + (t & 7) * 8;

    const int lane = t & 63;
    const int wave = t >> 6;
    const int wm = (wave >> 1) * 64;
    const int wn = (wave & 1) * 64;
    const int fr = lane & 15;          // fragment free-dim index
    const int fk = (lane >> 4) * 8;    // fragment k offset

    f32x4 acc[4][4] = {};

    for (int k0 = 0; k0 < K_DIM; k0 += 64) {
#pragma unroll
        for (int it = 0; it < 4; ++it) {
            load16(gA + k0 + it * 32 * K_DIM, lA + it * 32 * 64);
            load16(gB + k0 + it * 32 * K_DIM, lB + it * 32 * 64);
        }
        __syncthreads();   // drains vmcnt(0): staged data visible
#pragma unroll
        for (int kk = 0; kk < 64; kk += 32) {
            bf16x8 af[4], bf[4];
#pragma unroll
            for (int i = 0; i < 4; ++i)
                af[i] = *(const bf16x8*)(As + (wm + i * 16 + fr) * 64 + kk + fk);
#pragma unroll
            for (int j = 0; j < 4; ++j)
                bf[j] = *(const bf16x8*)(Bs + (wn + j * 16 + fr) * 64 + kk + fk);
#pragma unroll
            for (int i = 0; i < 4; ++i)
#pragma unroll
                for (int j = 0; j < 4; ++j)
                    acc[i][j] = __builtin_amdgcn_mfma_f32_16x16x32_bf16(
                        af[i], bf[j], acc[i][j], 0, 0, 0);
        }
        __syncthreads();   // all waves done reading before next stage
    }

    // epilogue: C/D layout col=lane&15 (n), row=(lane>>4)*4+reg (m)
    const int rb = (lane >> 4) * 4;
#pragma unroll
    for (int i = 0; i < 4; ++i) {
#pragma unroll
        for (int j = 0; j < 4; ++j) {
            int n = bn * 128 + wn + j * 16 + fr;
            float bv = bias[n];
#pragma unroll
            for (int r = 0; r < 4; ++r) {
                int m = bm * 128 + wm + i * 16 + rb + r;
                C[(size_t)m * N_DIM + n] = acc[i][j][r] + bv;
            }
        }
    }
}

extern "C" void kernel_launch(void* const* d_in, const int* in_sizes, int n_in,
                              void* d_out, int out_size, void* d_ws, size_t ws_size,
                              hipStream_t stream) {
    const float* x    = (const float*)d_in[0];  // 2048 x 4096
    const float* mask = (const float*)d_in[1];  // 4096 x 4096
    const float* W    = (const float*)d_in[2];  // 4096 x 4096
    const float* bias = (const float*)d_in[3];  // 4096
    float* out = (float*)d_out;                 // 2048 x 4096

    u16* Bt = (u16*)d_ws;                                   // N*K bf16 = 32 MB
    u16* xb = (u16*)d_ws + (size_t)N_DIM * K_DIM;           // M*K bf16 = 16 MB

    conv_x<<<(M_DIM * K_DIM) / (256 * 4), 256, 0, stream>>>(x, xb);
    mask_transpose<<<dim3(N_DIM / 64, K_DIM / 64), 256, 0, stream>>>(W, mask, Bt);
    gemm_bt<<<dim3(N_DIM / 128, M_DIM / 128), 256, 0, stream>>>(xb, Bt, bias, out);
}

// Round 3
// 253.403 us; speedup vs baseline: 1.1085x; 1.1085x over previous
//
#include <hip/hip_runtime.h>

#define M_DIM 2048
#define K_DIM 4096
#define N_DIM 4096

typedef unsigned short u16;
typedef __bf16 bf16x8 __attribute__((ext_vector_type(8)));
typedef float f32x4 __attribute__((ext_vector_type(4)));
typedef u16 u16x4 __attribute__((ext_vector_type(4)));
typedef u16 u16x8 __attribute__((ext_vector_type(8)));

// fp32 -> bf16 round-to-nearest-even
__device__ __forceinline__ u16 f2bf(float f) {
    unsigned int u = __float_as_uint(f);
    u += 0x7fffu + ((u >> 16) & 1u);
    return (u16)(u >> 16);
}

// async global->LDS, 16B per lane. LDS dest must be wave-uniform base + lane*16.
__device__ __forceinline__ void load16(const void* g, void* l) {
    __builtin_amdgcn_global_load_lds(
        (__attribute__((address_space(1))) const void*)g,
        (__attribute__((address_space(3))) void*)l,
        16, 0, 0);
}

// --------------- fused prep: x->bf16  AND  Bt = (mask? W:0)^T bf16 ----------
// blocks [0, 4096): transpose one 64x64 tile of W/mask -> Bt[n][k]
// blocks [4096, 8192): convert 2048 contiguous floats of x -> xb
// NOTE R2 bug was HERE (host call passed mask,W swapped) — kernel unchanged.
__global__ __launch_bounds__(256) void prep(const float* __restrict__ x,
                                            u16* __restrict__ xb,
                                            const float* __restrict__ W,
                                            const float* __restrict__ Msk,
                                            u16* __restrict__ Bt) {
    const int t = threadIdx.x;
    if (blockIdx.x >= 4096) {
        // ---- conv_x: 8 floats/thread ----
        size_t i = ((size_t)(blockIdx.x - 4096) * 256 + t) * 8;
        float4 v0 = *(const float4*)(x + i);
        float4 v1 = *(const float4*)(x + i + 4);
        u16x8 o;
        o[0] = f2bf(v0.x); o[1] = f2bf(v0.y); o[2] = f2bf(v0.z); o[3] = f2bf(v0.w);
        o[4] = f2bf(v1.x); o[5] = f2bf(v1.y); o[6] = f2bf(v1.z); o[7] = f2bf(v1.w);
        *(u16x8*)(xb + i) = o;
        return;
    }
    // ---- mask+transpose: 64x64 tile through LDS ----
    __shared__ __align__(16) u16 T[64][68];   // [k][n]
    const int n0 = (blockIdx.x & 63) * 64;
    const int k0 = (blockIdx.x >> 6) * 64;

    const int colq = (t & 15) * 4;   // n within tile, 4-wide
    const int row4 = t >> 4;         // k within tile, 16 rows/pass
#pragma unroll
    for (int p = 0; p < 4; ++p) {
        int row = row4 + p * 16;
        size_t g = (size_t)(k0 + row) * N_DIM + n0 + colq;
        float4 w = *(const float4*)(W + g);
        float4 m = *(const float4*)(Msk + g);
        u16x4 v;
        v.x = f2bf(m.x != 0.f ? w.x : 0.f);
        v.y = f2bf(m.y != 0.f ? w.y : 0.f);
        v.z = f2bf(m.z != 0.f ? w.z : 0.f);
        v.w = f2bf(m.w != 0.f ? w.w : 0.f);
        *(u16x4*)&T[row][colq] = v;
    }
    __syncthreads();

    const int kc  = (t & 7) * 8;     // k within tile, 8-wide
    const int nr0 = t >> 3;          // n within tile, 32 rows/pass
#pragma unroll
    for (int p = 0; p < 2; ++p) {
        int nr = nr0 + p * 32;
        u16x8 v;
#pragma unroll
        for (int i = 0; i < 8; ++i) v[i] = T[kc + i][nr];
        *(u16x8*)(Bt + (size_t)(n0 + nr) * K_DIM + k0 + kc) = v;
    }
}

// ---------------- gemm: C = xb @ Bt^T + bias, XOR-swizzled LDS --------------
// 128x128 tile, BK=64, 4 waves in 2x2, each wave 4x4 of 16x16x32 MFMA.
// LDS rows are 128 B (== 32 banks), so an identity layout puts every row of a
// fragment read on the same 4-bank group (measured 2.5e7 conflict cycles R1).
// Fix: lane t STAGES global k-chunk ((t&7)^((t>>3)&7)) into its fixed LDS slot
// (keeps the wave-uniform-base + lane*16 rule of global_load_lds), and
// fragment reads XOR (fr&7) back into the chunk index. All-constant, no
// runtime cost; spreads fragment reads uniformly over all 8 bank groups
// (8 lanes/group = the 1024B/instr minimum of 8 LDS phases).
__global__ __launch_bounds__(256) void gemm_bt(const u16* __restrict__ A,   // M x K bf16
                                               const u16* __restrict__ Bt,  // N x K bf16
                                               const float* __restrict__ bias,
                                               float* __restrict__ C) {
    __shared__ __align__(16) u16 As[128 * 64];
    __shared__ __align__(16) u16 Bs[128 * 64];

    const int t  = threadIdx.x;
    const int bn = blockIdx.x;
    const int bm = blockIdx.y;

    // staging: lane handles row (t>>3)+32*it, swizzled k-chunk (constant/thread)
    const int srow   = t >> 3;
    const int schunk = (t & 7) ^ (srow & 7);
    const u16* gA = A  + (size_t)(bm * 128 + srow) * K_DIM + schunk * 8;
    const u16* gB = Bt + (size_t)(bn * 128 + srow) * K_DIM + schunk * 8;
    u16* lA = As + t * 8;
    u16* lB = Bs + t * 8;

    const int lane = t & 63;
    const int wave = t >> 6;
    const int wm = (wave >> 1) * 64;
    const int wn = (wave & 1) * 64;
    const int fr = lane & 15;          // fragment free-dim index
    const int q  = lane >> 4;          // k-quad
    const int sw = fr & 7;             // row-phase for the XOR swizzle
    // physical u16 column of the 16B chunk holding global k = kk + q*8
    const int col0 = ((0 + q) ^ sw) * 8;   // kk = 0
    const int col1 = ((4 + q) ^ sw) * 8;   // kk = 32

    f32x4 acc[4][4] = {};

    for (int k0 = 0; k0 < K_DIM; k0 += 64) {
#pragma unroll
        for (int it = 0; it < 4; ++it) {
            load16(gA + k0 + it * 32 * K_DIM, lA + it * 2048);
            load16(gB + k0 + it * 32 * K_DIM, lB + it * 2048);
        }
        __syncthreads();   // drains vmcnt(0): staged data visible
#pragma unroll
        for (int kx = 0; kx < 2; ++kx) {
            const int col = kx ? col1 : col0;
            bf16x8 af[4], bfr[4];
#pragma unroll
            for (int i = 0; i < 4; ++i)
                af[i] = *(const bf16x8*)(As + (wm + i * 16 + fr) * 64 + col);
#pragma unroll
            for (int j = 0; j < 4; ++j)
                bfr[j] = *(const bf16x8*)(Bs + (wn + j * 16 + fr) * 64 + col);
#pragma unroll
            for (int i = 0; i < 4; ++i)
#pragma unroll
                for (int j = 0; j < 4; ++j)
                    acc[i][j] = __builtin_amdgcn_mfma_f32_16x16x32_bf16(
                        af[i], bfr[j], acc[i][j], 0, 0, 0);
        }
        __syncthreads();   // all waves done reading before next stage
    }

    // epilogue: C/D layout col=lane&15 (n), row=(lane>>4)*4+reg (m)
    const int rb = q * 4;
#pragma unroll
    for (int i = 0; i < 4; ++i) {
#pragma unroll
        for (int j = 0; j < 4; ++j) {
            int n = bn * 128 + wn + j * 16 + fr;
            float bv = bias[n];
#pragma unroll
            for (int r = 0; r < 4; ++r) {
                int m = bm * 128 + wm + i * 16 + rb + r;
                C[(size_t)m * N_DIM + n] = acc[i][j][r] + bv;
            }
        }
    }
}

extern "C" void kernel_launch(void* const* d_in, const int* in_sizes, int n_in,
                              void* d_out, int out_size, void* d_ws, size_t ws_size,
                              hipStream_t stream) {
    const float* x    = (const float*)d_in[0];  // 2048 x 4096
    const float* mask = (const float*)d_in[1];  // 4096 x 4096
    const float* W    = (const float*)d_in[2];  // 4096 x 4096
    const float* bias = (const float*)d_in[3];  // 4096
    float* out = (float*)d_out;                 // 2048 x 4096

    u16* Bt = (u16*)d_ws;                                   // N*K bf16 = 32 MB
    u16* xb = (u16*)d_ws + (size_t)N_DIM * K_DIM;           // M*K bf16 = 16 MB

    // prep signature is (x, xb, W, Msk, Bt) — R2 passed mask,W here. Fixed.
    prep<<<8192, 256, 0, stream>>>(x, xb, W, mask, Bt);
    gemm_bt<<<dim3(N_DIM / 128, M_DIM / 128), 256, 0, stream>>>(xb, Bt, bias, out);
}

// Round 4
// 252.061 us; speedup vs baseline: 1.1144x; 1.0053x over previous
//
#include <hip/hip_runtime.h>

#define M_DIM 2048
#define K_DIM 4096
#define N_DIM 4096

typedef unsigned short u16;
typedef unsigned int u32;
typedef __bf16 bf16x8 __attribute__((ext_vector_type(8)));
typedef float f32x4 __attribute__((ext_vector_type(4)));
typedef u16 u16x8 __attribute__((ext_vector_type(8)));

// fp32 -> bf16 round-to-nearest-even
__device__ __forceinline__ u16 f2bf(float f) {
    unsigned int u = __float_as_uint(f);
    u += 0x7fffu + ((u >> 16) & 1u);
    return (u16)(u >> 16);
}

// pack two fp32 -> (bf16(lo) | bf16(hi)<<16), RNE
__device__ __forceinline__ u32 pack2(float lo, float hi) {
    u32 a = __float_as_uint(lo); a += 0x7fffu + ((a >> 16) & 1u);
    u32 b = __float_as_uint(hi); b += 0x7fffu + ((b >> 16) & 1u);
    return (a >> 16) | (b & 0xffff0000u);
}

// async global->LDS, 16B per lane. LDS dest must be wave-uniform base + lane*16.
__device__ __forceinline__ void load16(const void* g, void* l) {
    __builtin_amdgcn_global_load_lds(
        (__attribute__((address_space(1))) const void*)g,
        (__attribute__((address_space(3))) void*)l,
        16, 0, 0);
}

// --------------- fused prep: x->bf16  AND  Bt = (mask? W:0)^T bf16 ----------
// blocks [0, 4096): transpose one 64x64 tile of W/mask -> Bt[n][k]
// blocks [4096, 8192): convert 2048 contiguous floats of x -> xb
//
// Transpose is u32-granular: a u32 holds the bf16 pair (k, k+1) for one n.
// LDS tile T32[n][kp] (kp = k/2, 32 u32/row = 128 B row stride) with a 16B
// chunk XOR swizzle: phys_chunk = (kp>>2) ^ ((n>>2)&7). Phase-1: 8 scalar
// ds_write_b32, banks = 4*((t&7)^(t>>5)) + (t>>3)&3 -> exactly 2 lanes/bank
// (free, m136). Phase-2: 2 ds_read_b128, 8 lanes cover one full 128 B row
// (conflict-free, same family as the gemm swizzle that measured 0 conflicts).
__global__ __launch_bounds__(256) void prep(const float* __restrict__ x,
                                            u16* __restrict__ xb,
                                            const float* __restrict__ W,
                                            const float* __restrict__ Msk,
                                            u16* __restrict__ Bt) {
    const int t = threadIdx.x;
    if (blockIdx.x >= 4096) {
        // ---- conv_x: 8 floats/thread ----
        size_t i = ((size_t)(blockIdx.x - 4096) * 256 + t) * 8;
        float4 v0 = *(const float4*)(x + i);
        float4 v1 = *(const float4*)(x + i + 4);
        u16x8 o;
        o[0] = f2bf(v0.x); o[1] = f2bf(v0.y); o[2] = f2bf(v0.z); o[3] = f2bf(v0.w);
        o[4] = f2bf(v1.x); o[5] = f2bf(v1.y); o[6] = f2bf(v1.z); o[7] = f2bf(v1.w);
        *(u16x8*)(xb + i) = o;
        return;
    }
    __shared__ __align__(16) u32 T32[64 * 32];   // [n][kp swizzled]
    const int n0 = (blockIdx.x & 63) * 64;
    const int k0 = (blockIdx.x >> 6) * 64;

    // ---- phase 1: read rows kL,kL+1 (128B-coalesced), pack, scatter to LDS --
    const int kL     = (t >> 3) * 2;       // 0..62 even; kp = t>>3 in 0..31
    const int pchunk = ((t >> 3) >> 2) ^ (t & 7);   // (kp>>2) ^ ((n>>2)&7)
    const int word   = (t >> 3) & 3;
#pragma unroll
    for (int p = 0; p < 2; ++p) {
        const int n4 = (t & 7) * 4 + 32 * p;        // (n4>>2)&7 == t&7 for i<4
        size_t g = (size_t)(k0 + kL) * N_DIM + n0 + n4;
        float4 w0 = *(const float4*)(W + g);
        float4 w1 = *(const float4*)(W + g + N_DIM);
        float4 m0 = *(const float4*)(Msk + g);
        float4 m1 = *(const float4*)(Msk + g + N_DIM);
        u32 v[4];
        v[0] = pack2(m0.x != 0.f ? w0.x : 0.f, m1.x != 0.f ? w1.x : 0.f);
        v[1] = pack2(m0.y != 0.f ? w0.y : 0.f, m1.y != 0.f ? w1.y : 0.f);
        v[2] = pack2(m0.z != 0.f ? w0.z : 0.f, m1.z != 0.f ? w1.z : 0.f);
        v[3] = pack2(m0.w != 0.f ? w0.w : 0.f, m1.w != 0.f ? w1.w : 0.f);
#pragma unroll
        for (int i = 0; i < 4; ++i)
            T32[(n4 + i) * 32 + pchunk * 4 + word] = v[i];
    }
    __syncthreads();

    // ---- phase 2: vector-read one swizzled 16B chunk, store 128B-coalesced --
    const int rchunk = t & 7;              // logical chunk (8 k values)
    const int rkey   = t >> 5;             // ((n>>2)&7), p drops out (32p>>2=8p)
    const int pc     = rchunk ^ rkey;
#pragma unroll
    for (int p = 0; p < 2; ++p) {
        const int n = (t >> 3) + 32 * p;
        uint4 v = *(const uint4*)&T32[n * 32 + pc * 4];
        *(uint4*)(Bt + (size_t)(n0 + n) * K_DIM + k0 + rchunk * 8) = v;
    }
}

// ---------------- gemm: C = xb @ Bt^T + bias, XOR-swizzled LDS --------------
// UNCHANGED from R3 (869 TF = m97-structure plateau; SQ_LDS_BANK_CONFLICT=0).
__global__ __launch_bounds__(256) void gemm_bt(const u16* __restrict__ A,   // M x K bf16
                                               const u16* __restrict__ Bt,  // N x K bf16
                                               const float* __restrict__ bias,
                                               float* __restrict__ C) {
    __shared__ __align__(16) u16 As[128 * 64];
    __shared__ __align__(16) u16 Bs[128 * 64];

    const int t  = threadIdx.x;
    const int bn = blockIdx.x;
    const int bm = blockIdx.y;

    const int srow   = t >> 3;
    const int schunk = (t & 7) ^ (srow & 7);
    const u16* gA = A  + (size_t)(bm * 128 + srow) * K_DIM + schunk * 8;
    const u16* gB = Bt + (size_t)(bn * 128 + srow) * K_DIM + schunk * 8;
    u16* lA = As + t * 8;
    u16* lB = Bs + t * 8;

    const int lane = t & 63;
    const int wave = t >> 6;
    const int wm = (wave >> 1) * 64;
    const int wn = (wave & 1) * 64;
    const int fr = lane & 15;          // fragment free-dim index
    const int q  = lane >> 4;          // k-quad
    const int sw = fr & 7;             // row-phase for the XOR swizzle
    const int col0 = ((0 + q) ^ sw) * 8;   // kk = 0
    const int col1 = ((4 + q) ^ sw) * 8;   // kk = 32

    f32x4 acc[4][4] = {};

    for (int k0 = 0; k0 < K_DIM; k0 += 64) {
#pragma unroll
        for (int it = 0; it < 4; ++it) {
            load16(gA + k0 + it * 32 * K_DIM, lA + it * 2048);
            load16(gB + k0 + it * 32 * K_DIM, lB + it * 2048);
        }
        __syncthreads();
#pragma unroll
        for (int kx = 0; kx < 2; ++kx) {
            const int col = kx ? col1 : col0;
            bf16x8 af[4], bfr[4];
#pragma unroll
            for (int i = 0; i < 4; ++i)
                af[i] = *(const bf16x8*)(As + (wm + i * 16 + fr) * 64 + col);
#pragma unroll
            for (int j = 0; j < 4; ++j)
                bfr[j] = *(const bf16x8*)(Bs + (wn + j * 16 + fr) * 64 + col);
#pragma unroll
            for (int i = 0; i < 4; ++i)
#pragma unroll
                for (int j = 0; j < 4; ++j)
                    acc[i][j] = __builtin_amdgcn_mfma_f32_16x16x32_bf16(
                        af[i], bfr[j], acc[i][j], 0, 0, 0);
        }
        __syncthreads();
    }

    const int rb = q * 4;
#pragma unroll
    for (int i = 0; i < 4; ++i) {
#pragma unroll
        for (int j = 0; j < 4; ++j) {
            int n = bn * 128 + wn + j * 16 + fr;
            float bv = bias[n];
#pragma unroll
            for (int r = 0; r < 4; ++r) {
                int m = bm * 128 + wm + i * 16 + rb + r;
                C[(size_t)m * N_DIM + n] = acc[i][j][r] + bv;
            }
        }
    }
}

extern "C" void kernel_launch(void* const* d_in, const int* in_sizes, int n_in,
                              void* d_out, int out_size, void* d_ws, size_t ws_size,
                              hipStream_t stream) {
    const float* x    = (const float*)d_in[0];  // 2048 x 4096
    const float* mask = (const float*)d_in[1];  // 4096 x 4096
    const float* W    = (const float*)d_in[2];  // 4096 x 4096
    const float* bias = (const float*)d_in[3];  // 4096
    float* out = (float*)d_out;                 // 2048 x 4096

    u16* Bt = (u16*)d_ws;                                   // N*K bf16 = 32 MB
    u16* xb = (u16*)d_ws + (size_t)N_DIM * K_DIM;           // M*K bf16 = 16 MB

    // prep signature is (x, xb, W, Msk, Bt) — keep argument order exact.
    prep<<<8192, 256, 0, stream>>>(x, xb, W, mask, Bt);
    gemm_bt<<<dim3(N_DIM / 128, M_DIM / 128), 256, 0, stream>>>(xb, Bt, bias, out);
}